// Round 4
// baseline (58421.021 us; speedup 1.0000x reference)
//
#include <hip/hip_runtime.h>
#include <cstdio>

#define NROWS 8640      // D*T sequential steps
#define HDIM  1024
#define NWG   64        // persistent workgroups
#define RPW   16        // rows per WG
#define LINE_W 32       // floats per (replica,WG) line: 8 chunks x 16B = 128B
#define NREP  8         // publish replicas (cuts same-line reader fan-in 8x)
#define REPSTR (NWG * LINE_W)   // replica stride in floats

typedef float vf4 __attribute__((ext_vector_type(4)));

__device__ __forceinline__ float fsig(float x)  { return 1.f / (1.f + __expf(-x)); }
__device__ __forceinline__ float ftanh(float x) { return 2.f / (1.f + __expf(-2.f * x)) - 1.f; }

// LLC-coherent 16B ops (sc0 sc1: bypass non-coherent per-XCD L1/L2)
__device__ __forceinline__ vf4 llc_load_f4(const float* p) {
  vf4 v;
  asm volatile("global_load_dwordx4 %0, %1, off sc0 sc1\n\ts_waitcnt vmcnt(0)"
               : "=v"(v) : "v"(p) : "memory");
  return v;
}
__device__ __forceinline__ void llc_store_f4(float* p, vf4 v) {
  asm volatile("global_store_dwordx4 %0, %1, off sc0 sc1" :: "v"(p), "v"(v) : "memory");
}

__device__ __forceinline__ float dot4(vf4 a, vf4 b) {
  return a.x*b.x + a.y*b.y + a.z*b.z + a.w*b.w;
}

// full-wave butterfly sum (xor-only: measured 0 bank conflicts)
#define WRED(x) { x += __shfl_xor(x,32,64); x += __shfl_xor(x,16,64); \
                  x += __shfl_xor(x, 8,64); x += __shfl_xor(x, 4,64); \
                  x += __shfl_xor(x, 2,64); x += __shfl_xor(x, 1,64); }

// 64 WGs x 512 threads (8 waves). WG g owns rows [16g,16g+16); wave w owns rows
// 16g+2w, 16g+2w+1 of all 5 matrices (weights in VGPRs). Per phase each wave
// publishes one 16B chunk [v0 v1 seq pad] to 8 replicas (lanes 0-7, one store
// inst). Thread t polls chunk (srcWG=t>>3, wave=t&7) in replica (wg&7) -> only
// 8 readers per address per retry round. LDS h double-buffered: phase A reads
// sh_a, scatters h_o to sh_b; phase B reads sh_b, scatters h to sh_a.
__global__ __launch_bounds__(512, 2) void scan_kernel(
    const float* __restrict__ pre_ho, const float* __restrict__ pre_i,
    const float* __restrict__ pre_g,  const float* __restrict__ pre_f,
    const float* __restrict__ pre_o,
    const float* __restrict__ w_t,  const float* __restrict__ w_ih,
    const float* __restrict__ w_gh, const float* __restrict__ w_fo,
    const float* __restrict__ w_oh,
    float* __restrict__ lines0, float* __restrict__ lines1,
    float* __restrict__ hs, float* __restrict__ cs)
{
  __shared__ float sh_a[HDIM];   // h at phase-A entry
  __shared__ float sh_b[HDIM];   // h_o at phase-B entry

  const int tid  = threadIdx.x;
  const int lane = tid & 63;
  const int w    = tid >> 6;          // wave 0..7
  const int wg   = blockIdx.x;
  const int r0   = wg * RPW + 2 * w;  // this wave's first row
  const int myrow = r0 + lane;        // valid for lane<2

  for (int i = tid; i < HDIM; i += 512) { sh_a[i] = 0.f; sh_b[i] = 0.f; }

  // weight fragments: Wf[mat][row][m]; mat: 0=w_t 1=w_oh 2=w_ih 3=w_gh 4=w_fo
  vf4 Wf[5][2][4];
  {
    const float* Wp[5] = { w_t, w_oh, w_ih, w_gh, w_fo };
#pragma unroll
    for (int mt = 0; mt < 5; ++mt)
#pragma unroll
      for (int rr = 0; rr < 2; ++rr)
#pragma unroll
        for (int m = 0; m < 4; ++m)
          Wf[mt][rr][m] = *(const vf4*)(Wp[mt] + (long)(r0+rr)*HDIM + m*256 + 4*lane);
  }

  // per-row state in lanes 0,1 of the owning wave
  float cprev = 0.f, oo = 0.f;
  float ph = 0.f, po = 0.f, pi = 0.f, pg = 0.f, pf = 0.f;
  if (lane < 2) {
    ph = pre_ho[myrow]; po = pre_o[myrow];
    pi = pre_i[myrow];  pg = pre_g[myrow]; pf = pre_f[myrow];
  }

  // poll: thread t -> chunk (srcWG=t>>3, wave=t&7), replica wg&7
  const long pofs = (long)(wg & 7) * REPSTR + (long)(tid >> 3) * LINE_W + (long)(tid & 7) * 4;
  const int  dsh  = 2 * tid;
  const float* pollA = lines0 + pofs;
  const float* pollB = lines1 + pofs;
  // publish: lanes 0..7 store replica `lane`
  const long pubofs = (long)lane * REPSTR + (long)wg * LINE_W + (long)w * 4;
  float* pubA = lines0 + pubofs;
  float* pubB = lines1 + pubofs;

  __syncthreads();

  for (int n = 0; n < NROWS; ++n) {
    const int tgtA = 2*n + 1, tgtB = 2*n + 2;

    // ======== phase A: h_o = sig(ph + 2*W_t h_prev), o = sig(po + W_oh h_prev)
    {
      vf4 h0 = *(const vf4*)(sh_a + 4*lane);
      vf4 h1 = *(const vf4*)(sh_a + 4*lane + 256);
      vf4 h2 = *(const vf4*)(sh_a + 4*lane + 512);
      vf4 h3 = *(const vf4*)(sh_a + 4*lane + 768);
      float t0 = dot4(Wf[0][0][0],h0)+dot4(Wf[0][0][1],h1)+dot4(Wf[0][0][2],h2)+dot4(Wf[0][0][3],h3);
      float t1 = dot4(Wf[0][1][0],h0)+dot4(Wf[0][1][1],h1)+dot4(Wf[0][1][2],h2)+dot4(Wf[0][1][3],h3);
      float o0 = dot4(Wf[1][0][0],h0)+dot4(Wf[1][0][1],h1)+dot4(Wf[1][0][2],h2)+dot4(Wf[1][0][3],h3);
      float o1 = dot4(Wf[1][1][0],h0)+dot4(Wf[1][1][1],h1)+dot4(Wf[1][1][2],h2)+dot4(Wf[1][1][3],h3);
      WRED(t0); WRED(t1); WRED(o0); WRED(o1);
      float hov = 0.f;
      if (lane < 2) {
        float ut = lane ? t1 : t0;
        float uo = lane ? o1 : o0;
        hov = fsig(ph + 2.f * ut);
        oo  = fsig(po + uo);
      }
      float d0 = __shfl(hov, 0, 64);
      float d1 = __shfl(hov, 1, 64);
      if (lane < NREP) {
        vf4 d; d.x = d0; d.y = d1; d.z = __int_as_float(tgtA); d.w = 0.f;
        llc_store_f4(pubA, d);
      }
    }
    {
      vf4 d;
      do { d = llc_load_f4(pollA); } while (__float_as_int(d.z) < tgtA);
      *(float2*)(sh_b + dsh) = make_float2(d.x, d.y);
    }
    __syncthreads();                       // sh_b now holds h_o

    // ======== phase B: gates from h_o; c,h update
    {
      // prefetch next step's pre_* early (overlaps dot compute)
      float ph2 = 0.f, po2 = 0.f, pi2 = 0.f, pg2 = 0.f, pf2 = 0.f;
      if (lane < 2 && n + 1 < NROWS) {
        long o2 = (long)(n+1)*HDIM + myrow;
        ph2 = pre_ho[o2]; po2 = pre_o[o2];
        pi2 = pre_i[o2];  pg2 = pre_g[o2]; pf2 = pre_f[o2];
      }
      vf4 h0 = *(const vf4*)(sh_b + 4*lane);
      vf4 h1 = *(const vf4*)(sh_b + 4*lane + 256);
      vf4 h2 = *(const vf4*)(sh_b + 4*lane + 512);
      vf4 h3 = *(const vf4*)(sh_b + 4*lane + 768);
      float i0 = dot4(Wf[2][0][0],h0)+dot4(Wf[2][0][1],h1)+dot4(Wf[2][0][2],h2)+dot4(Wf[2][0][3],h3);
      float i1 = dot4(Wf[2][1][0],h0)+dot4(Wf[2][1][1],h1)+dot4(Wf[2][1][2],h2)+dot4(Wf[2][1][3],h3);
      float g0 = dot4(Wf[3][0][0],h0)+dot4(Wf[3][0][1],h1)+dot4(Wf[3][0][2],h2)+dot4(Wf[3][0][3],h3);
      float g1 = dot4(Wf[3][1][0],h0)+dot4(Wf[3][1][1],h1)+dot4(Wf[3][1][2],h2)+dot4(Wf[3][1][3],h3);
      float f0 = dot4(Wf[4][0][0],h0)+dot4(Wf[4][0][1],h1)+dot4(Wf[4][0][2],h2)+dot4(Wf[4][0][3],h3);
      float f1 = dot4(Wf[4][1][0],h0)+dot4(Wf[4][1][1],h1)+dot4(Wf[4][1][2],h2)+dot4(Wf[4][1][3],h3);
      WRED(i0); WRED(i1); WRED(g0); WRED(g1); WRED(f0); WRED(f1);
      float hhv = 0.f;
      if (lane < 2) {
        float ui = lane ? i1 : i0;
        float ug = lane ? g1 : g0;
        float uf = lane ? f1 : f0;
        float ii = fsig(pi + ui);
        float gg = ftanh(pg + ug);
        float ff = fsig(pf + uf);
        float cc = ff * cprev + ii * gg;
        hhv = oo * ftanh(cc);
        cprev = cc;
        hs[(long)n*HDIM + myrow] = hhv;
        cs[(long)n*HDIM + myrow] = cc;
      }
      float d0 = __shfl(hhv, 0, 64);
      float d1 = __shfl(hhv, 1, 64);
      if (lane < NREP) {
        vf4 d; d.x = d0; d.y = d1; d.z = __int_as_float(tgtB); d.w = 0.f;
        llc_store_f4(pubB, d);
      }
      ph = ph2; po = po2; pi = pi2; pg = pg2; pf = pf2;
    }
    {
      vf4 d;
      do { d = llc_load_f4(pollB); } while (__float_as_int(d.z) < tgtB);
      *(float2*)(sh_a + dsh) = make_float2(d.x, d.y);
    }
    __syncthreads();                       // sh_a now holds new h
  }
}

// ---------- generic accumulating GEMM: C[n,h] += sum_k A[rowmap(n),k]*B[h,k] ----------
__global__ __launch_bounds__(256) void gemm_acc(
    float* __restrict__ C, const float* __restrict__ A, const float* __restrict__ B,
    int K, int shift, int minn)
{
  __shared__ float Asf[16 * 68];
  __shared__ float Bsf[16 * 68];
  const int tid = threadIdx.x;
  const int h0  = blockIdx.x * 64;
  const int n0  = blockIdx.y * 64;
  const int r   = tid >> 2;
  const int kq  = (tid & 3) << 2;
  const int tx  = tid & 15, ty = tid >> 4;

  int arow = n0 + r;
  int src  = arow - shift; if (src < 0) src += NROWS;
  const bool avalid = (arow >= minn);
  const float* Ap = A + (long)src * K + kq;
  const float* Bp = B + (long)(h0 + r) * K + kq;

  vf4 acc0 = {0.f,0.f,0.f,0.f}, acc1 = {0.f,0.f,0.f,0.f};
  vf4 acc2 = {0.f,0.f,0.f,0.f}, acc3 = {0.f,0.f,0.f,0.f};
  const vf4 zero = {0.f,0.f,0.f,0.f};

  for (int k0 = 0; k0 < K; k0 += 16) {
    vf4 av = avalid ? *(const vf4*)(Ap + k0) : zero;
    vf4 bv = *(const vf4*)(Bp + k0);
    __syncthreads();
    Asf[(kq+0)*68 + r] = av.x;  Asf[(kq+1)*68 + r] = av.y;
    Asf[(kq+2)*68 + r] = av.z;  Asf[(kq+3)*68 + r] = av.w;
    Bsf[(kq+0)*68 + r] = bv.x;  Bsf[(kq+1)*68 + r] = bv.y;
    Bsf[(kq+2)*68 + r] = bv.z;  Bsf[(kq+3)*68 + r] = bv.w;
    __syncthreads();
#pragma unroll
    for (int c = 0; c < 16; ++c) {
      vf4 a = *(const vf4*)(Asf + c*68 + (ty << 2));
      vf4 b = *(const vf4*)(Bsf + c*68 + (tx << 2));
      acc0 += a.x * b;
      acc1 += a.y * b;
      acc2 += a.z * b;
      acc3 += a.w * b;
    }
  }
  float* cp = C + (long)(n0 + (ty << 2)) * HDIM + h0 + (tx << 2);
  { vf4 t = *(vf4*)(cp + 0*HDIM); t += acc0; *(vf4*)(cp + 0*HDIM) = t; }
  { vf4 t = *(vf4*)(cp + 1*HDIM); t += acc1; *(vf4*)(cp + 1*HDIM) = t; }
  { vf4 t = *(vf4*)(cp + 2*HDIM); t += acc2; *(vf4*)(cp + 2*HDIM) = t; }
  { vf4 t = *(vf4*)(cp + 3*HDIM); t += acc3; *(vf4*)(cp + 3*HDIM) = t; }
}

__global__ void bias_init(float* __restrict__ out, const float* __restrict__ bias) {
  int i = blockIdx.x * blockDim.x + threadIdx.x;
  vf4 v = {0.f,0.f,0.f,0.f};
  if (bias) { int h = (i << 2) & (HDIM - 1); v = *(const vf4*)(bias + h); }
  *((vf4*)out + i) = v;
}

__global__ void sigmoid_k(float* __restrict__ e) {
  int i = blockIdx.x * blockDim.x + threadIdx.x;
  vf4 v = *((vf4*)e + i);
  v.x = fsig(v.x); v.y = fsig(v.y); v.z = fsig(v.z); v.w = fsig(v.w);
  *((vf4*)e + i) = v;
}

extern "C" void kernel_launch(void* const* d_in, const int* in_sizes, int n_in,
                              void* d_out, int out_size, void* d_ws, size_t ws_size,
                              hipStream_t stream) {
  const float* x    = (const float*)d_in[0];
  const float* xw   = (const float*)d_in[1];
  const float* w_ix = (const float*)d_in[2];
  const float* w_ih = (const float*)d_in[3];
  const float* w_ie = (const float*)d_in[4];
  const float* b_i  = (const float*)d_in[5];
  const float* w_fx = (const float*)d_in[6];
  const float* w_fo = (const float*)d_in[7];
  const float* w_fe = (const float*)d_in[8];
  const float* b_f  = (const float*)d_in[9];
  const float* w_ox = (const float*)d_in[10];
  const float* w_oh = (const float*)d_in[11];
  const float* w_oe = (const float*)d_in[12];
  const float* b_o  = (const float*)d_in[13];
  const float* w_gx = (const float*)d_in[14];
  const float* w_gh = (const float*)d_in[15];
  const float* b_g  = (const float*)d_in[16];
  const float* w_d  = (const float*)d_in[17];
  const float* w_w  = (const float*)d_in[18];
  const float* w_m  = (const float*)d_in[19];
  const float* w_t  = (const float*)d_in[20];
  const float* w_e  = (const float*)d_in[21];
  const float* b_e  = (const float*)d_in[22];

  const long S = (long)NROWS * HDIM;
  float* ws_f   = (float*)d_ws;
  float* pre_ho = ws_f + 0*S;
  float* pre_i  = ws_f + 1*S;
  float* pre_g  = ws_f + 2*S;
  float* pre_f  = ws_f + 3*S;
  float* pre_o  = ws_f + 4*S;
  float* e_buf  = ws_f + 5*S;
  float* lines0 = ws_f + 6*S;
  float* lines1 = lines0 + NREP*REPSTR;

  size_t need = (size_t)(6*S + 2*NREP*REPSTR) * sizeof(float);
  if (ws_size < need) {
    fprintf(stderr, "kernel_launch: ws too small (have %zu, need %zu)\n", ws_size, need);
    return;
  }

  dim3 ggrid(HDIM/64, NROWS/64);

  bias_init<<<NROWS, 256, 0, stream>>>(pre_i, b_i);
  bias_init<<<NROWS, 256, 0, stream>>>(pre_g, b_g);
  bias_init<<<NROWS, 256, 0, stream>>>(pre_f, b_f);
  bias_init<<<NROWS, 256, 0, stream>>>(pre_o, b_o);
  bias_init<<<NROWS, 256, 0, stream>>>(e_buf, b_e);
  bias_init<<<NROWS, 256, 0, stream>>>(pre_ho, nullptr);

  gemm_acc<<<ggrid, 256, 0, stream>>>(e_buf, xw, w_e, 64, 0, 0);
  sigmoid_k<<<NROWS, 256, 0, stream>>>(e_buf);

  gemm_acc<<<ggrid, 256, 0, stream>>>(pre_i, x, w_ix, 512, 0, 0);
  gemm_acc<<<ggrid, 256, 0, stream>>>(pre_g, x, w_gx, 512, 0, 0);
  gemm_acc<<<ggrid, 256, 0, stream>>>(pre_f, x, w_fx, 512, 0, 0);
  gemm_acc<<<ggrid, 256, 0, stream>>>(pre_o, x, w_ox, 512, 0, 0);
  gemm_acc<<<ggrid, 256, 0, stream>>>(pre_i, e_buf, w_ie, 1024, 0, 0);
  gemm_acc<<<ggrid, 256, 0, stream>>>(pre_f, e_buf, w_fe, 1024, 0, 0);
  gemm_acc<<<ggrid, 256, 0, stream>>>(pre_o, e_buf, w_oe, 1024, 0, 0);
  gemm_acc<<<ggrid, 256, 0, stream>>>(pre_ho, x, w_d, 512,   96,   96);
  gemm_acc<<<ggrid, 256, 0, stream>>>(pre_ho, x, w_w, 512,  576,  672);
  gemm_acc<<<ggrid, 256, 0, stream>>>(pre_ho, x, w_m, 512, 2784, 2688);

  hipMemsetAsync(lines0, 0, 2 * NREP * REPSTR * sizeof(float), stream);

  float* hs = (float*)d_out;
  float* cs = hs + S;
  scan_kernel<<<NWG, 512, 0, stream>>>(pre_ho, pre_i, pre_g, pre_f, pre_o,
                                       w_t, w_ih, w_gh, w_fo, w_oh,
                                       lines0, lines1, hs, cs);
}